// Round 1
// baseline (344.609 us; speedup 1.0000x reference)
//
#include <hip/hip_runtime.h>

#define N_NODES 50000
#define N_EDGES 800000
#define D 64
#define K 3

// ---------------- Kernel 1: xgw[n, 0:192] = x @ g ; xgw[n, 192:256] = x @ root
__global__ void gemm_xw_kernel(const float* __restrict__ x,
                               const float* __restrict__ g,
                               const float* __restrict__ root,
                               float* __restrict__ xgw) {
    __shared__ float sW[64 * 256];   // 64 KB: W[i][j], j<192 from g, else root
    __shared__ float sx[64];
    const int tid = threadIdx.x;
    for (int idx = tid; idx < 64 * 256; idx += 256) {
        int i = idx >> 8;
        int j = idx & 255;
        sW[idx] = (j < 192) ? g[i * 192 + j] : root[i * 64 + (j - 192)];
    }
    __syncthreads();
    for (int row = blockIdx.x; row < N_NODES; row += gridDim.x) {
        if (tid < 64) sx[tid] = x[(size_t)row * 64 + tid];
        __syncthreads();
        float acc = 0.f;
#pragma unroll
        for (int i = 0; i < 64; ++i)
            acc += sx[i] * sW[i * 256 + tid];   // sx broadcast, sW conflict-free
        xgw[(size_t)row * 256 + tid] = acc;
        __syncthreads();
    }
}

// ---------------- Kernel 2: per-edge gather + gaussian weights + atomic scatter
__global__ void edge_kernel(const float* __restrict__ xgw,
                            const int* __restrict__ ei,     // [2, E]
                            const float* __restrict__ pseudo,
                            const float* __restrict__ mu,
                            const float* __restrict__ sigma,
                            float* __restrict__ summed,     // [N, 64] zeroed
                            float* __restrict__ cnt) {      // [N] zeroed
    const int lane = threadIdx.x & 63;
    int wave = (blockIdx.x * blockDim.x + threadIdx.x) >> 6;
    const int nw = (gridDim.x * blockDim.x) >> 6;
    const float mu0 = mu[0], mu1 = mu[1], mu2 = mu[2];
    const float s0 = sigma[0], s1 = sigma[1], s2 = sigma[2];
    const float c0 = -0.5f / (1e-14f + s0 * s0);
    const float c1 = -0.5f / (1e-14f + s1 * s1);
    const float c2 = -0.5f / (1e-14f + s2 * s2);
    for (int e = wave; e < N_EDGES; e += nw) {
        const int s  = ei[e];
        const int dd = ei[N_EDGES + e];
        const float u = pseudo[e];
        const float d0 = u - mu0, d1 = u - mu1, d2 = u - mu2;
        const float w0 = expf(c0 * d0 * d0);
        const float w1 = expf(c1 * d1 * d1);
        const float w2 = expf(c2 * d2 * d2);
        const float* base = xgw + (size_t)s * 256;
        const float m = w0 * base[lane] + w1 * base[64 + lane] + w2 * base[128 + lane];
        atomicAdd(summed + (size_t)dd * 64 + lane, m);
        if (lane == 0) atomicAdd(cnt + dd, 1.0f);
    }
}

// ---------------- Kernel 3: epilogue  silu(summed/max(cnt,1) + xroot + bias + x)
__global__ void final_kernel(const float* __restrict__ summed,
                             const float* __restrict__ cnt,
                             const float* __restrict__ xgw,
                             const float* __restrict__ x,
                             const float* __restrict__ bias,
                             float* __restrict__ out) {
    const int idx = blockIdx.x * 256 + threadIdx.x;
    if (idx >= N_NODES * D) return;
    const int n = idx >> 6;
    const int d = idx & 63;
    const float c = cnt[n];
    float v = summed[idx] / fmaxf(c, 1.0f)
            + xgw[(size_t)n * 256 + 192 + d]
            + bias[d]
            + x[idx];
    out[idx] = v / (1.0f + expf(-v));   // silu
}

extern "C" void kernel_launch(void* const* d_in, const int* in_sizes, int n_in,
                              void* d_out, int out_size, void* d_ws, size_t ws_size,
                              hipStream_t stream) {
    const float* x     = (const float*)d_in[0];
    const int*   ei    = (const int*)d_in[1];
    const float* ea    = (const float*)d_in[2];
    const float* g     = (const float*)d_in[3];
    const float* mu    = (const float*)d_in[4];
    const float* sigma = (const float*)d_in[5];
    const float* root  = (const float*)d_in[6];
    const float* bias  = (const float*)d_in[7];
    float* out = (float*)d_out;

    char* ws = (char*)d_ws;
    const size_t xgw_bytes    = (size_t)N_NODES * 256 * sizeof(float); // 51.2 MB
    const size_t summed_bytes = (size_t)N_NODES * 64 * sizeof(float);  // 12.8 MB
    const size_t cnt_bytes    = (size_t)N_NODES * sizeof(float);       // 0.2 MB
    float* xgw    = (float*)ws;
    float* summed = (float*)(ws + xgw_bytes);
    float* cnt    = (float*)(ws + xgw_bytes + summed_bytes);

    // zero the accumulators (summed and cnt are contiguous)
    hipMemsetAsync(summed, 0, summed_bytes + cnt_bytes, stream);

    gemm_xw_kernel<<<2048, 256, 0, stream>>>(x, g, root, xgw);
    edge_kernel<<<4096, 256, 0, stream>>>(xgw, ei, ea, mu, sigma, summed, cnt);
    final_kernel<<<(N_NODES * D + 255) / 256, 256, 0, stream>>>(summed, cnt, xgw, x, bias, out);
}